// Round 7
// baseline (25914.432 us; speedup 1.0000x reference)
//
#include <hip/hip_runtime.h>
#include <stdint.h>

// LSTMClassifier: 2-layer LSTM (B=128,T=1024,I=256,H=512) + FC(512->1).
// Persistent grid-resident kernel, layers pipelined (layer1 lags 1 step).
// R7: EPOCH-IN-DWORD dataflow sync. Each h element is a dword:
//   [bf16 value | 16-bit epoch tag]; tag(h[t]) = t+1.
// Dword stores are atomic => readers retry on tag mismatch; no ordering
// between distinct addresses is ever assumed => NO fences, NO buffer_wbl2/
// buffer_inv (the ~17us/step L2-walk cost of R3/R5), NO grid barrier.
// h traffic uses sc0sc1 (cache-bypass, IF$-coherent) relaxed atomics.
// WAR on the depth-4 h ring is throttled by relaxed monotonic progress
// slots (stale reads => extra waiting only; conservative-safe).
//
// ws layout (bytes):
//   Wp0 [2048][768]  bf16 packed rows r=u*4+q  (cols: 0..255=W_ih0, 256..767=W_hh0)
//   Wp1 [2048][1024] bf16 packed                (cols: 0..511=W_ih1, 512..1023=W_hh1)
//   bp0/bp1 [2048] f32 (b_ih+b_hh, packed order)
//   h0d  u32[4][128][512] layer-0 h ring (value<<16 | epoch)
//   h1d  u32[4][128][512] layer-1 h ring
//   cnt  progress slots: 8 groups x 64 dwords (one single-writer slot/block)

#define T_STEPS 1024
#define NBLK 512
#define NTHR 256

#define WS_WP0   0u
#define WS_WP1   3145728u
#define WS_BP0   7340032u
#define WS_BP1   7348224u
#define WS_H0    7356416u
#define WS_H1    8404992u
#define WS_CNT   9453568u
#define HZ       524288      // total h dwords (2 rings x 4 x 65536)
#define CNT_U32  512

typedef __bf16 bf16x8 __attribute__((ext_vector_type(8)));
typedef float  f32x4  __attribute__((ext_vector_type(4)));

__device__ __forceinline__ unsigned short f2bf(float f) {
    union { float f; uint32_t u; } a; a.f = f;
    uint32_t r = a.u + 0x7fffu + ((a.u >> 16) & 1u);
    return (unsigned short)(r >> 16);
}
__device__ __forceinline__ float bf2f(unsigned short u) {
    union { uint32_t u; float f; } a; a.u = ((uint32_t)u) << 16; return a.f;
}
__device__ __forceinline__ float sigm(float x)  { return 1.f / (1.f + __expf(-x)); }
__device__ __forceinline__ float tanh_f(float x){ return 2.f / (1.f + __expf(-2.f * x)) - 1.f; }

// ---- pre-pack weights to bf16, gate-interleaved rows r = u*4 + q (q: i,f,g,o) ----
__global__ void k_pack(const float* __restrict__ Wih0, const float* __restrict__ Whh0,
                       const float* __restrict__ Wih1, const float* __restrict__ Whh1,
                       unsigned short* __restrict__ Wp0, unsigned short* __restrict__ Wp1)
{
    int t = blockIdx.x * blockDim.x + threadIdx.x;
    const int N0 = 2048 * 768;
    const int N1 = 2048 * 1024;
    if (t < N0) {
        int r = t / 768, k = t - r * 768;
        int u = r >> 2, q = r & 3, row = q * 512 + u;
        float v = (k < 256) ? Wih0[row * 256 + k] : Whh0[row * 512 + (k - 256)];
        Wp0[t] = f2bf(v);
    } else if (t < N0 + N1) {
        int t2 = t - N0;
        int r = t2 >> 10, k = t2 & 1023;
        int u = r >> 2, q = r & 3, row = q * 512 + u;
        float v = (k < 512) ? Wih1[row * 512 + k] : Whh1[row * 512 + (k - 512)];
        Wp1[t2] = f2bf(v);
    }
}

// ---- biases (packed), zero h rings (epoch 0 = never valid), zero progress ----
__global__ void k_misc(const float* __restrict__ bih0, const float* __restrict__ bhh0,
                       const float* __restrict__ bih1, const float* __restrict__ bhh1,
                       float* __restrict__ bp0, float* __restrict__ bp1,
                       uint32_t* __restrict__ hd, unsigned* __restrict__ cnt)
{
    int t = blockIdx.x * blockDim.x + threadIdx.x;
    if (t < 2048) {
        int u = t >> 2, q = t & 3, row = q * 512 + u;
        bp0[t] = bih0[row] + bhh0[row];
    } else if (t < 4096) {
        int r = t - 2048; int u = r >> 2, q = r & 3, row = q * 512 + u;
        bp1[r] = bih1[row] + bhh1[row];
    } else if (t < 4096 + HZ) {
        hd[t - 4096] = 0;
    } else if (t < 4096 + HZ + CNT_U32) {
        cnt[t - (4096 + HZ)] = 0;
    }
}

// ---- persistent LSTM ----
// NKW: ksteps(32) per wave; KTOT: total K; KS: boundary src0/src1; L0: layer-0 flag
template<int NKW, int KTOT, int KS, bool L0>
__device__ __forceinline__ void run_layer(
    int b0, int ut0, int g0, int w, int col, int quad, int tid,
    const float* __restrict__ x,
    const unsigned short* __restrict__ Wp,
    const float* __restrict__ bp,
    uint32_t* h0d, uint32_t* h1d,
    unsigned* slots, int myslot,
    float (*red)[16][68])
{
    const int bA = b0 + col;  // A-fragment row (batch index)

    // B fragments (weights) -> AGPR-resident for the whole run (pinned).
    uint4 Bf[4][NKW];
    #pragma unroll
    for (int f = 0; f < 4; ++f) {
        const unsigned short* wrow = Wp + (g0 + f * 16 + col) * KTOT + w * (NKW * 32) + quad * 8;
        #pragma unroll
        for (int ks = 0; ks < NKW; ++ks)
            Bf[f][ks] = *(const uint4*)(wrow + ks * 32);
    }
    #pragma unroll
    for (int f = 0; f < 4; ++f) {
        #pragma unroll
        for (int ks = 0; ks < NKW; ++ks) {
            uint32_t c0 = Bf[f][ks].x, c1 = Bf[f][ks].y, c2 = Bf[f][ks].z, c3 = Bf[f][ks].w;
            asm volatile("" : "+a"(c0), "+a"(c1), "+a"(c2), "+a"(c3));
            Bf[f][ks].x = c0; Bf[f][ks].y = c1; Bf[f][ks].z = c2; Bf[f][ks].w = c3;
        }
    }

    const int bl = tid >> 4, ul = tid & 15;      // elementwise domain: 16 batch x 16 units
    const f32x4 bias = *(const f32x4*)(bp + g0 + ul * 4);
    float c = 0.f;                               // cell state, register-resident

    // Per-kstep A source offsets. x offsets in floats; h offsets in DWORDS (unit idx).
    int  offA[NKW];
    bool s0[NKW];
    #pragma unroll
    for (int ks = 0; ks < NKW; ++ks) {
        int kg = w * (NKW * 32) + ks * 32 + quad * 8;
        if (kg < KS) {
            s0[ks] = true;
            offA[ks] = L0 ? (bA * (T_STEPS * 256) + kg) : (bA * 512 + kg);
        } else {
            s0[ks] = false;
            offA[ks] = L0 ? (bA * 512 + (kg - 256)) : (bA * 512 + (kg - 512));
        }
    }

    for (int s = 0; s <= T_STEPS; ++s) {
        const bool active = L0 ? (s < T_STEPS) : (s >= 1);

        // WAR throttle: writing step s overwrites ring content of step s-4,
        // consumed during macro-step s-3; wait until all group blocks report
        // completion of s-3 (progress value >= s-2). Stale reads => wait more.
        if (tid < 64) {
            const int need = s - 2;
            if (need > 0) {
                for (;;) {
                    int v = (int)__hip_atomic_load(slots + tid, __ATOMIC_RELAXED,
                                                   __HIP_MEMORY_SCOPE_SYSTEM);
                    if (__all(v >= need)) break;
                    __builtin_amdgcn_s_sleep(1);
                }
            }
        }

        if (active) {
            const int t = L0 ? s : (s - 1);
            bf16x8 Af[NKW];

            // x slices (L0 only): plain cached fp32 loads -> bf16
            if (L0) {
                const float* xb = x + t * 256;
                #pragma unroll
                for (int ks = 0; ks < NKW; ++ks) {
                    if (s0[ks]) {
                        const float* p = xb + offA[ks];
                        float4 lo = *(const float4*)p;
                        float4 hi = *(const float4*)(p + 4);
                        bf16x8 v;
                        v[0]=(__bf16)lo.x; v[1]=(__bf16)lo.y; v[2]=(__bf16)lo.z; v[3]=(__bf16)lo.w;
                        v[4]=(__bf16)hi.x; v[5]=(__bf16)hi.y; v[6]=(__bf16)hi.z; v[7]=(__bf16)hi.w;
                        Af[ks] = v;
                    }
                }
            }

            // h slices: spin until every dword carries the expected epoch.
            //   srcA = h0[s-1] (tag s)  -- both layers;  valid when s>=1
            //   srcB = h1[s-2] (tag s-1) -- L1 only;      valid when s>=2
            const bool hA_ok = (s >= 1);
            const bool hB_ok = (s >= 2);
            const uint32_t* pA = h0d + ((s + 3) & 3) * 65536;
            const uint32_t* pB = h1d + ((s + 2) & 3) * 65536;
            const uint32_t tagA = (uint32_t)s, tagB = (uint32_t)(s - 1);
            const bool anyh = L0 ? hA_ok : true;

            if (anyh) {
                for (;;) {
                    bool ok = true;
                    uint32_t raw[NKW][8];
                    #pragma unroll
                    for (int ks = 0; ks < NKW; ++ks) {
                        const bool ish  = L0 ? (!s0[ks]) : true;
                        if (!ish) continue;
                        const bool useA = L0 ? true : s0[ks];
                        const bool val  = useA ? hA_ok : hB_ok;
                        if (!val) continue;
                        const uint32_t* p = (useA ? pA : pB) + offA[ks];
                        #pragma unroll
                        for (int j = 0; j < 8; ++j)
                            raw[ks][j] = __hip_atomic_load(p + j, __ATOMIC_RELAXED,
                                                           __HIP_MEMORY_SCOPE_SYSTEM);
                        const uint32_t tg = useA ? tagA : tagB;
                        #pragma unroll
                        for (int j = 0; j < 8; ++j)
                            ok = ok && ((raw[ks][j] & 0xffffu) == tg);
                    }
                    if (__all((int)ok)) {
                        #pragma unroll
                        for (int ks = 0; ks < NKW; ++ks) {
                            const bool ish  = L0 ? (!s0[ks]) : true;
                            if (!ish) continue;
                            const bool useA = L0 ? true : s0[ks];
                            const bool val  = useA ? hA_ok : hB_ok;
                            if (!val) continue;
                            uint4 r;
                            r.x = (raw[ks][0] >> 16) | (raw[ks][1] & 0xffff0000u);
                            r.y = (raw[ks][2] >> 16) | (raw[ks][3] & 0xffff0000u);
                            r.z = (raw[ks][4] >> 16) | (raw[ks][5] & 0xffff0000u);
                            r.w = (raw[ks][6] >> 16) | (raw[ks][7] & 0xffff0000u);
                            Af[ks] = __builtin_bit_cast(bf16x8, r);
                        }
                        break;
                    }
                    __builtin_amdgcn_s_sleep(1);
                }
            }
            // zero-out h slices for the initial step(s) (h_{-1} = 0)
            #pragma unroll
            for (int ks = 0; ks < NKW; ++ks) {
                const bool ish  = L0 ? (!s0[ks]) : true;
                if (!ish) continue;
                const bool useA = L0 ? true : s0[ks];
                const bool val  = useA ? hA_ok : hB_ok;
                if (!val) {
                    uint4 z = {0u, 0u, 0u, 0u};
                    Af[ks] = __builtin_bit_cast(bf16x8, z);
                }
            }

            f32x4 acc[4] = { f32x4{0,0,0,0}, f32x4{0,0,0,0}, f32x4{0,0,0,0}, f32x4{0,0,0,0} };
            #pragma unroll
            for (int ks = 0; ks < NKW; ++ks) {
                #pragma unroll
                for (int f = 0; f < 4; ++f)
                    acc[f] = __builtin_amdgcn_mfma_f32_16x16x32_bf16(
                        Af[ks], __builtin_bit_cast(bf16x8, Bf[f][ks]), acc[f], 0, 0, 0);
            }
            #pragma unroll
            for (int f = 0; f < 4; ++f) {
                #pragma unroll
                for (int r = 0; r < 4; ++r)
                    red[w][quad * 4 + r][f * 16 + col] = acc[f][r];
            }
        }
        __syncthreads();           // red[] written by all waves (also gates stores behind throttle)
        if (active) {
            f32x4 g = bias;
            #pragma unroll
            for (int ww = 0; ww < 4; ++ww)
                g += *(const f32x4*)&red[ww][bl][ul * 4];
            float ig = sigm(g[0]), fg = sigm(g[1]), gc = tanh_f(g[2]), og = sigm(g[3]);
            c = fg * c + ig * gc;
            float h = og * tanh_f(c);
            // value<<16 | epoch; single atomic dword => self-validating datum
            const uint32_t tagW = L0 ? (uint32_t)(s + 1) : (uint32_t)s;
            uint32_t* hw = (L0 ? h0d + (s & 3) * 65536
                               : h1d + ((s + 3) & 3) * 65536)
                         + (b0 + bl) * 512 + (ut0 + ul);
            __hip_atomic_store(hw, ((uint32_t)f2bf(h) << 16) | tagW,
                               __ATOMIC_RELAXED, __HIP_MEMORY_SCOPE_SYSTEM);
        }
        __syncthreads();           // red[] reads done before next step's dump
        // publish progress: this block finished macro-step s (all reads done)
        if (tid == 0)
            __hip_atomic_store(slots + myslot, (unsigned)(s + 1),
                               __ATOMIC_RELAXED, __HIP_MEMORY_SCOPE_SYSTEM);
    }
}

__global__ __launch_bounds__(NTHR, 2) void lstm_persistent(
    const float* __restrict__ x,
    const unsigned short* __restrict__ Wp0, const unsigned short* __restrict__ Wp1,
    const float* __restrict__ bp0, const float* __restrict__ bp1,
    uint32_t* __restrict__ h0d, uint32_t* __restrict__ h1d,
    unsigned* __restrict__ cnt)
{
    __shared__ alignas(16) float red[4][16][68];   // 4 K-split waves x [16b][64g(+pad)]
    const int bid   = blockIdx.x;
    const int g     = bid & 7;          // batch-tile group (independent sync domain)
    const int rest  = bid >> 3;         // 0..63: pid within group
    const int layer = rest & 1;
    const int ut    = rest >> 1;        // 0..31 unit-tile
    const int b0    = g * 16;
    const int ut0   = ut * 16;
    const int g0    = ut * 64;          // packed gate-row base (= ut0*4)
    const int tid   = threadIdx.x;
    const int w = tid >> 6, lane = tid & 63, col = lane & 15, quad = lane >> 4;

    unsigned* slots = cnt + g * 64;
    const int myslot = rest;

    // per-group h rings (batch rows b0..b0+15 only are touched by this group)
    if (layer == 0)
        run_layer<6, 768, 256, true >(b0, ut0, g0, w, col, quad, tid, x, Wp0, bp0, h0d, h1d, slots, myslot, red);
    else
        run_layer<8, 1024, 512, false>(b0, ut0, g0, w, col, quad, tid, x, Wp1, bp1, h0d, h1d, slots, myslot, red);
}

// ---- final FC head: logits[b] = h1[1023][b,:] . fc_w + fc_b ----
__global__ void k_fc(const uint32_t* __restrict__ h1d3, const float* __restrict__ fcw,
                     const float* __restrict__ fcb, float* __restrict__ out)
{
    int b = threadIdx.x;
    if (b < 128) {
        const uint32_t* hr = h1d3 + b * 512;
        float acc = 0.f;
        for (int u = 0; u < 512; ++u)
            acc += bf2f((unsigned short)(hr[u] >> 16)) * fcw[u];
        out[b] = acc + fcb[0];
    }
}

extern "C" void kernel_launch(void* const* d_in, const int* in_sizes, int n_in,
                              void* d_out, int out_size, void* d_ws, size_t ws_size,
                              hipStream_t stream)
{
    const float* x    = (const float*)d_in[0];
    const float* Wih0 = (const float*)d_in[1];
    const float* Whh0 = (const float*)d_in[2];
    const float* bih0 = (const float*)d_in[3];
    const float* bhh0 = (const float*)d_in[4];
    const float* Wih1 = (const float*)d_in[5];
    const float* Whh1 = (const float*)d_in[6];
    const float* bih1 = (const float*)d_in[7];
    const float* bhh1 = (const float*)d_in[8];
    const float* fcw  = (const float*)d_in[9];
    const float* fcb  = (const float*)d_in[10];

    char* ws = (char*)d_ws;
    unsigned short* Wp0 = (unsigned short*)(ws + WS_WP0);
    unsigned short* Wp1 = (unsigned short*)(ws + WS_WP1);
    float* bp0 = (float*)(ws + WS_BP0);
    float* bp1 = (float*)(ws + WS_BP1);
    uint32_t* h0d = (uint32_t*)(ws + WS_H0);
    uint32_t* h1d = (uint32_t*)(ws + WS_H1);
    unsigned* cnt = (unsigned*)(ws + WS_CNT);

    const int npack = 2048 * 768 + 2048 * 1024;
    k_pack<<<(npack + 255) / 256, 256, 0, stream>>>(Wih0, Whh0, Wih1, Whh1, Wp0, Wp1);
    const int nmisc = 4096 + HZ + CNT_U32;
    k_misc<<<(nmisc + 255) / 256, 256, 0, stream>>>(bih0, bhh0, bih1, bhh1, bp0, bp1, h0d, cnt);

    lstm_persistent<<<NBLK, NTHR, 0, stream>>>(x, Wp0, Wp1, bp0, bp1, h0d, h1d, cnt);

    // h1[1023] lives in ring slot 1023&3 = 3
    k_fc<<<1, 128, 0, stream>>>(h1d + 3 * 65536, fcw, fcb, (float*)d_out);
}